// Round 11
// baseline (203.449 us; speedup 1.0000x reference)
//
#include <hip/hip_runtime.h>
#include <math.h>

#define BBATCH 64
#define LL 200
#define DD 300
#define PP 16
#define EPSV 1e-12f
#define KG 320          // global K-pad (10 chunks of 32)
#define PS 328          // maxsim LDS row stride in halfs (656 B: 4-bank row shift)
#define NCH 10
#define SRS 324         // prep LDS row stride in f32 (zeros 300..323 so frag/emit reads are unguarded)

typedef _Float16 f16x8 __attribute__((ext_vector_type(8)));
typedef float f32x4v __attribute__((ext_vector_type(4)));

// ---------------- prep: MFMA norms + f16 conversion + ksq frag table ---------------------
// (UNCHANGED from r10: passed, absmax preserved, -11 us vs f32-VALU norms.)
__global__ __launch_bounds__(256) void prep_kernel(const float* __restrict__ s1,
                                                   const float* __restrict__ s2,
                                                   const float* __restrict__ kern,
                                                   float* __restrict__ n1inv,
                                                   _Float16* __restrict__ n2inv,
                                                   _Float16* __restrict__ h1,
                                                   _Float16* __restrict__ h2,
                                                   _Float16* __restrict__ ksqt) {
    const int grp   = blockIdx.x;   // 0..6 (32-row groups)
    const int which = blockIdx.y;
    const int b     = blockIdx.z;
    const float* s  = which ? s2 : s1;
    _Float16* hout  = which ? h2 : h1;
    const int r0    = grp * 32;
    const int t     = threadIdx.x;

    __shared__ float    sr[32][SRS];   // 41,472 B
    __shared__ _Float16 kqf[640 * 8];  // 10,240 B: f16(k^2), B-frag layout (= ksqt layout)

    // stage s rows (coalesced float4; rows >= 200 zeroed)
    for (int idx = t; idx < 32 * 75; idx += 256) {
        int r = idx / 75, c4 = (idx - r * 75) * 4;
        int row = r0 + r;
        float4 v = make_float4(0.f, 0.f, 0.f, 0.f);
        if (row < LL) v = *(const float4*)&s[((size_t)b * LL + row) * DD + c4];
        *(float4*)&sr[r][c4] = v;
    }
    // zero tail cols 300..323
    for (int idx = t; idx < 32 * 24; idx += 256) {
        int r = idx / 24, cc = 300 + (idx - r * 24);
        sr[r][cc] = 0.f;
    }
    // build kqf[ent=(ch*4+quad)*16+p][e] = f16(kern[p][ch*32+quad*8+e]^2)
    for (int ent = t; ent < 640; ent += 256) {
        int ch = ent >> 6, rem = ent & 63;
        int quad = rem >> 4, p = rem & 15;
        int k0 = ch * 32 + quad * 8;
        f16x8 h;
        if (k0 + 8 <= DD) {
            float4 a = *(const float4*)&kern[p * DD + k0];
            float4 d = *(const float4*)&kern[p * DD + k0 + 4];
            h[0] = (_Float16)(a.x * a.x); h[1] = (_Float16)(a.y * a.y);
            h[2] = (_Float16)(a.z * a.z); h[3] = (_Float16)(a.w * a.w);
            h[4] = (_Float16)(d.x * d.x); h[5] = (_Float16)(d.y * d.y);
            h[6] = (_Float16)(d.z * d.z); h[7] = (_Float16)(d.w * d.w);
        } else {
#pragma unroll
            for (int e = 0; e < 8; e++) {
                float kv = (k0 + e < DD) ? kern[p * DD + k0 + e] : 0.f;
                h[e] = (_Float16)(kv * kv);
            }
        }
        *(f16x8*)&kqf[ent * 8] = h;
    }
    __syncthreads();

    const int lane = t & 63;
    const int w    = t >> 6;

    if (w < 2) {
        // norms via MFMA: row group rg = w
        const int rg   = w;
        const int c    = lane & 15;
        const int quad = lane >> 4;
        f32x4v nacc = (f32x4v)0.f;
#pragma unroll
        for (int ch = 0; ch < NCH; ch++) {
            float4 a = *(const float4*)&sr[rg * 16 + c][ch * 32 + quad * 8];
            float4 d = *(const float4*)&sr[rg * 16 + c][ch * 32 + quad * 8 + 4];
            f16x8 sa;
            sa[0] = (_Float16)(a.x * a.x); sa[1] = (_Float16)(a.y * a.y);
            sa[2] = (_Float16)(a.z * a.z); sa[3] = (_Float16)(a.w * a.w);
            sa[4] = (_Float16)(d.x * d.x); sa[5] = (_Float16)(d.y * d.y);
            sa[6] = (_Float16)(d.z * d.z); sa[7] = (_Float16)(d.w * d.w);
            f16x8 bk = *(const f16x8*)&kqf[((ch * 4 + quad) * 16 + c) * 8];
            nacc = __builtin_amdgcn_mfma_f32_16x16x32_f16(sa, bk, nacc, 0, 0, 0);
        }
#pragma unroll
        for (int r = 0; r < 4; r++) {
            int row = r0 + rg * 16 + quad * 4 + r;
            if (row < LL) {
                float inv = 1.0f / sqrtf(fmaxf(nacc[r], EPSV));
                if (which) n2inv[((size_t)b * LL + row) * PP + c] = (_Float16)inv;
                else       n1inv[((size_t)b * LL + row) * PP + c] = inv;
            }
        }
    } else {
        // emit f16 rows (K-padded to 320; tail from zeroed sr)
        const int base = (w - 2) * 640;
        for (int u = base + lane; u < base + 640; u += 64) {
            int r = u / 40, e0 = (u - r * 40) * 8;
            int row = r0 + r;
            if (row < LL) {
                float4 a = *(const float4*)&sr[r][e0];
                float4 d = *(const float4*)&sr[r][e0 + 4];
                f16x8 h;
                h[0] = (_Float16)a.x; h[1] = (_Float16)a.y; h[2] = (_Float16)a.z; h[3] = (_Float16)a.w;
                h[4] = (_Float16)d.x; h[5] = (_Float16)d.y; h[6] = (_Float16)d.z; h[7] = (_Float16)d.w;
                *(f16x8*)&hout[((size_t)b * LL + row) * KG + e0] = h;
            }
        }
    }

    if (which == 1 && grp == 6 && b == 0) {
        for (int ent = t; ent < 640; ent += 256)
            *(f16x8*)&ksqt[(size_t)ent * 8] = *(const f16x8*)&kqf[ent * 8];
    }
}

// ---------------- maxsim: full-j in one block, fused n1inv epilogue ----------------------
// r10 accounting: maxsim ran 2 sequential blocks/CU (j halves) + a reduce kernel combining
// them. This version folds ALL 200 j-rows into one block: B 200xPS + n2 200 rows + kq in
// LDS = 147.8 KB (<160). Grid 256 = b(64) x iblk(2) x pgrp(2) = exactly 1 block/CU:
// one staging phase instead of two, -12% MFMA work (overlap tile 12 replaces duplicated
// halves), part round-trip + reduce kernel deleted, out written directly scaled by n1inv.
// 13 j-tiles: jt 0..11 at rows 16*jt, jt 12 at rows 184..199 (8-row overlap; max
// idempotent). Inner loop = r9's proven distance-1 LDS pipeline, unchanged.
// i-overlap (rows 72..127 written by both iblk blocks) is bit-identical -> benign.
__global__ __launch_bounds__(256, 1) void maxsim_kernel(const _Float16* __restrict__ h1,
                                                        const _Float16* __restrict__ h2,
                                                        const _Float16* __restrict__ ksqt,
                                                        const _Float16* __restrict__ n2inv,
                                                        const float* __restrict__ n1inv,
                                                        float* __restrict__ out) {
    extern __shared__ __align__(16) char smem[];
    _Float16* h2s = (_Float16*)smem;          // 200*PS halfs = 131,200 B
    _Float16* n2s = h2s + 200 * PS;           // 200*16 halfs =   6,400 B
    _Float16* kqs = n2s + 200 * PP;           // 5120 halfs   =  10,240 B (total 147,840)

    const int blk  = blockIdx.x;
    const int b    = blk & 63;
    const int v    = blk >> 6;                // 0..3
    const int iblk = v & 1;
    const int pgrp = v >> 1;
    const int i0   = iblk ? 72 : 0;
    const int t    = threadIdx.x;

    const int lane = t & 63;
    const int w    = t >> 6;                  // 4 waves
    const int c    = lane & 15;
    const int quad = lane >> 4;
    const int ibase = i0 + w * 32;

    // A fragments: global -> registers (20 x b128 = 80 VGPR; h1 is L2/L3-hot)
    f16x8 af[2][NCH];
    {
        const _Float16* g1 = h1 + (size_t)b * LL * KG;
#pragma unroll
        for (int it = 0; it < 2; it++)
#pragma unroll
            for (int ch = 0; ch < NCH; ch++)
                af[it][ch] = *(const f16x8*)&g1[(size_t)(ibase + it * 16 + c) * KG + ch * 32 + quad * 8];
    }

    // stage FULL B tile (200 rows) + n2 (200 rows) + ksq table into LDS
    {
        const _Float16* g2 = h2 + (size_t)b * LL * KG;
        for (int idx = t; idx < 200 * 40; idx += 256) {
            int r = idx / 40, q = idx - r * 40;
            *(f16x8*)&h2s[r * PS + q * 8] = *(const f16x8*)&g2[(size_t)idx * 8];
        }
        const _Float16* gn = n2inv + (size_t)b * LL * PP;
        for (int idx = t; idx < 400; idx += 256)
            *(f16x8*)&n2s[idx * 8] = *(const f16x8*)&gn[(size_t)idx * 8];
        for (int idx = t; idx < 640; idx += 256)
            *(f16x8*)&kqs[idx * 8] = *(const f16x8*)&ksqt[(size_t)idx * 8];
    }
    __syncthreads();

    for (int pp = 0; pp < 4; pp++) {
        const int p0 = pgrp * 8 + pp * 2;
        float rmax[2][2][4];                   // [pq][it][r], persists across passes
#pragma unroll
        for (int pq = 0; pq < 2; pq++)
#pragma unroll
            for (int it = 0; it < 2; it++)
#pragma unroll
                for (int r = 0; r < 4; r++) rmax[pq][it][r] = -INFINITY;

#pragma unroll
        for (int pass = 0; pass < 7; pass++) {
            const int jn  = (pass < 6) ? 2 : 1;           // 13 j-tiles: {2x6, 1}
            const int jb0 = (pass < 6) ? pass * 32 : 184; // row base of first tile
            const int jb1 = pass * 32 + 16;               // second tile (only when jn==2)
            f32x4v acc[2][2][2];                          // [pq][it][jt] = 64 acc regs
#pragma unroll
            for (int pq = 0; pq < 2; pq++)
#pragma unroll
                for (int it = 0; it < 2; it++)
#pragma unroll
                    for (int jt = 0; jt < 2; jt++) acc[pq][it][jt] = (f32x4v)0.f;

            // prime ch=0 (current regs); all inner-loop loads are LDS
            f16x8 kq0 = *(const f16x8*)&kqs[quad * 128 + p0 * 8];
            f16x8 kq1 = *(const f16x8*)&kqs[quad * 128 + p0 * 8 + 8];
            f16x8 hb0 = *(const f16x8*)&h2s[(jb0 + c) * PS + quad * 8];
            f16x8 hb1 = hb0;
            if (jn > 1) hb1 = *(const f16x8*)&h2s[(jb1 + c) * PS + quad * 8];

#pragma unroll
            for (int ch = 0; ch < NCH; ch++) {
                // issue ch+1 loads FIRST: consumed at top of next iter (~119 cyc later)
                f16x8 kq0n = kq0, kq1n = kq1, hb0n = hb0, hb1n = hb1;
                if (ch < NCH - 1) {
                    kq0n = *(const f16x8*)&kqs[(ch + 1) * 512 + quad * 128 + p0 * 8];
                    kq1n = *(const f16x8*)&kqs[(ch + 1) * 512 + quad * 128 + p0 * 8 + 8];
                    hb0n = *(const f16x8*)&h2s[(jb0 + c) * PS + (ch + 1) * 32 + quad * 8];
                    if (jn > 1)
                        hb1n = *(const f16x8*)&h2s[(jb1 + c) * PS + (ch + 1) * 32 + quad * 8];
                }
                // fold ksq into the A side: 4 pk_muls feed up to 8 MFMAs
                f16x8 sa00 = af[0][ch] * kq0;
                f16x8 sa10 = af[1][ch] * kq0;
                f16x8 sa01 = af[0][ch] * kq1;
                f16x8 sa11 = af[1][ch] * kq1;
                acc[0][0][0] = __builtin_amdgcn_mfma_f32_16x16x32_f16(sa00, hb0, acc[0][0][0], 0, 0, 0);
                acc[0][1][0] = __builtin_amdgcn_mfma_f32_16x16x32_f16(sa10, hb0, acc[0][1][0], 0, 0, 0);
                acc[1][0][0] = __builtin_amdgcn_mfma_f32_16x16x32_f16(sa01, hb0, acc[1][0][0], 0, 0, 0);
                acc[1][1][0] = __builtin_amdgcn_mfma_f32_16x16x32_f16(sa11, hb0, acc[1][1][0], 0, 0, 0);
                if (jn > 1) {
                    acc[0][0][1] = __builtin_amdgcn_mfma_f32_16x16x32_f16(sa00, hb1, acc[0][0][1], 0, 0, 0);
                    acc[0][1][1] = __builtin_amdgcn_mfma_f32_16x16x32_f16(sa10, hb1, acc[0][1][1], 0, 0, 0);
                    acc[1][0][1] = __builtin_amdgcn_mfma_f32_16x16x32_f16(sa01, hb1, acc[1][0][1], 0, 0, 0);
                    acc[1][1][1] = __builtin_amdgcn_mfma_f32_16x16x32_f16(sa11, hb1, acc[1][1][1], 0, 0, 0);
                }
                kq0 = kq0n; kq1 = kq1n; hb0 = hb0n; hb1 = hb1n;
            }
            // fold this pass into rmax: scale cols by n2, max over j-tiles
#pragma unroll
            for (int pq = 0; pq < 2; pq++) {
                {
                    float n2 = (float)n2s[(jb0 + c) * PP + p0 + pq];
#pragma unroll
                    for (int it = 0; it < 2; it++)
#pragma unroll
                        for (int r = 0; r < 4; r++)
                            rmax[pq][it][r] = fmaxf(rmax[pq][it][r], acc[pq][it][0][r] * n2);
                }
                if (jn > 1) {
                    float n2 = (float)n2s[(jb1 + c) * PP + p0 + pq];
#pragma unroll
                    for (int it = 0; it < 2; it++)
#pragma unroll
                        for (int r = 0; r < 4; r++)
                            rmax[pq][it][r] = fmaxf(rmax[pq][it][r], acc[pq][it][1][r] * n2);
                }
            }
        }

        // reduce over j-col (lane bits 0..3), scale by n1inv, write out directly
#pragma unroll
        for (int pq = 0; pq < 2; pq++) {
#pragma unroll
            for (int m = 1; m <= 8; m <<= 1)
#pragma unroll
                for (int it = 0; it < 2; it++)
#pragma unroll
                    for (int r = 0; r < 4; r++)
                        rmax[pq][it][r] = fmaxf(rmax[pq][it][r], __shfl_xor(rmax[pq][it][r], m));
            if (c == 0) {
#pragma unroll
                for (int it = 0; it < 2; it++)
#pragma unroll
                    for (int r = 0; r < 4; r++) {
                        int i = ibase + it * 16 + quad * 4 + r;   // < 200 by construction
                        size_t o = ((size_t)b * LL + i) * PP + p0 + pq;
                        out[o] = rmax[pq][it][r] * n1inv[o];
                    }
            }
        }
    }
}

extern "C" void kernel_launch(void* const* d_in, const int* in_sizes, int n_in,
                              void* d_out, int out_size, void* d_ws, size_t ws_size,
                              hipStream_t stream) {
    const float* sent1  = (const float*)d_in[0];   // (64,200,300) f32
    const float* sent2  = (const float*)d_in[1];   // (64,200,300) f32
    const float* kernel = (const float*)d_in[2];   // (16,300)     f32
    float* out = (float*)d_out;                    // (64,200,16)  f32

    char* ws = (char*)d_ws;
    float*    n1inv = (float*)ws;                  ws += (size_t)BBATCH * LL * PP * 4;   // 0.82 MB
    _Float16* n2inv = (_Float16*)ws;               ws += (size_t)BBATCH * LL * PP * 2;   // 0.41 MB
    _Float16* h1    = (_Float16*)ws;               ws += (size_t)BBATCH * LL * KG * 2;   // 8.19 MB
    _Float16* h2    = (_Float16*)ws;               ws += (size_t)BBATCH * LL * KG * 2;   // 8.19 MB
    _Float16* ksqt  = (_Float16*)ws;               // 10 KB (total ~17.6 MB)

    prep_kernel<<<dim3(7, 2, BBATCH), 256, 0, stream>>>(sent1, sent2, kernel,
                                                        n1inv, n2inv, h1, h2, ksqt);

    const int lds_bytes = (200 * PS + 200 * PP + 5120) * 2;   // 147,840 B -> 1 block/CU
    hipFuncSetAttribute((const void*)maxsim_kernel,
                        hipFuncAttributeMaxDynamicSharedMemorySize, lds_bytes);
    maxsim_kernel<<<dim3(256, 1, 1), 256, lds_bytes, stream>>>(h1, h2, ksqt, n2inv, n1inv, out);
}

// Round 12
// 127.143 us; speedup vs baseline: 1.6002x; 1.6002x over previous
//
#include <hip/hip_runtime.h>
#include <math.h>

#define BBATCH 64
#define LL 200
#define DD 300
#define PP 16
#define EPSV 1e-12f
#define KG 320          // global K-pad (10 chunks of 32)
#define PS 328          // maxsim LDS row stride in halfs (656 B: 4-bank row shift)
#define NCH 10
#define SRS 324         // prep LDS row stride in f32 (zeros 300..323 so frag/emit reads are unguarded)

typedef _Float16 f16x8 __attribute__((ext_vector_type(8)));
typedef float f32x4v __attribute__((ext_vector_type(4)));

// ---------------- prep: MFMA norms + f16 conversion + ksq frag table ---------------------
// (UNCHANGED from r10: passed, absmax preserved, -11 us vs f32-VALU norms.)
__global__ __launch_bounds__(256) void prep_kernel(const float* __restrict__ s1,
                                                   const float* __restrict__ s2,
                                                   const float* __restrict__ kern,
                                                   float* __restrict__ n1inv,
                                                   _Float16* __restrict__ n2inv,
                                                   _Float16* __restrict__ h1,
                                                   _Float16* __restrict__ h2,
                                                   _Float16* __restrict__ ksqt) {
    const int grp   = blockIdx.x;   // 0..6 (32-row groups)
    const int which = blockIdx.y;
    const int b     = blockIdx.z;
    const float* s  = which ? s2 : s1;
    _Float16* hout  = which ? h2 : h1;
    const int r0    = grp * 32;
    const int t     = threadIdx.x;

    __shared__ float    sr[32][SRS];   // 41,472 B
    __shared__ _Float16 kqf[640 * 8];  // 10,240 B: f16(k^2), B-frag layout (= ksqt layout)

    // stage s rows (coalesced float4; rows >= 200 zeroed)
    for (int idx = t; idx < 32 * 75; idx += 256) {
        int r = idx / 75, c4 = (idx - r * 75) * 4;
        int row = r0 + r;
        float4 v = make_float4(0.f, 0.f, 0.f, 0.f);
        if (row < LL) v = *(const float4*)&s[((size_t)b * LL + row) * DD + c4];
        *(float4*)&sr[r][c4] = v;
    }
    // zero tail cols 300..323
    for (int idx = t; idx < 32 * 24; idx += 256) {
        int r = idx / 24, cc = 300 + (idx - r * 24);
        sr[r][cc] = 0.f;
    }
    // build kqf[ent=(ch*4+quad)*16+p][e] = f16(kern[p][ch*32+quad*8+e]^2)
    for (int ent = t; ent < 640; ent += 256) {
        int ch = ent >> 6, rem = ent & 63;
        int quad = rem >> 4, p = rem & 15;
        int k0 = ch * 32 + quad * 8;
        f16x8 h;
        if (k0 + 8 <= DD) {
            float4 a = *(const float4*)&kern[p * DD + k0];
            float4 d = *(const float4*)&kern[p * DD + k0 + 4];
            h[0] = (_Float16)(a.x * a.x); h[1] = (_Float16)(a.y * a.y);
            h[2] = (_Float16)(a.z * a.z); h[3] = (_Float16)(a.w * a.w);
            h[4] = (_Float16)(d.x * d.x); h[5] = (_Float16)(d.y * d.y);
            h[6] = (_Float16)(d.z * d.z); h[7] = (_Float16)(d.w * d.w);
        } else {
#pragma unroll
            for (int e = 0; e < 8; e++) {
                float kv = (k0 + e < DD) ? kern[p * DD + k0 + e] : 0.f;
                h[e] = (_Float16)(kv * kv);
            }
        }
        *(f16x8*)&kqf[ent * 8] = h;
    }
    __syncthreads();

    const int lane = t & 63;
    const int w    = t >> 6;

    if (w < 2) {
        // norms via MFMA: row group rg = w
        const int rg   = w;
        const int c    = lane & 15;
        const int quad = lane >> 4;
        f32x4v nacc = (f32x4v)0.f;
#pragma unroll
        for (int ch = 0; ch < NCH; ch++) {
            float4 a = *(const float4*)&sr[rg * 16 + c][ch * 32 + quad * 8];
            float4 d = *(const float4*)&sr[rg * 16 + c][ch * 32 + quad * 8 + 4];
            f16x8 sa;
            sa[0] = (_Float16)(a.x * a.x); sa[1] = (_Float16)(a.y * a.y);
            sa[2] = (_Float16)(a.z * a.z); sa[3] = (_Float16)(a.w * a.w);
            sa[4] = (_Float16)(d.x * d.x); sa[5] = (_Float16)(d.y * d.y);
            sa[6] = (_Float16)(d.z * d.z); sa[7] = (_Float16)(d.w * d.w);
            f16x8 bk = *(const f16x8*)&kqf[((ch * 4 + quad) * 16 + c) * 8];
            nacc = __builtin_amdgcn_mfma_f32_16x16x32_f16(sa, bk, nacc, 0, 0, 0);
        }
#pragma unroll
        for (int r = 0; r < 4; r++) {
            int row = r0 + rg * 16 + quad * 4 + r;
            if (row < LL) {
                float inv = 1.0f / sqrtf(fmaxf(nacc[r], EPSV));
                if (which) n2inv[((size_t)b * LL + row) * PP + c] = (_Float16)inv;
                else       n1inv[((size_t)b * LL + row) * PP + c] = inv;
            }
        }
    } else {
        // emit f16 rows (K-padded to 320; tail from zeroed sr)
        const int base = (w - 2) * 640;
        for (int u = base + lane; u < base + 640; u += 64) {
            int r = u / 40, e0 = (u - r * 40) * 8;
            int row = r0 + r;
            if (row < LL) {
                float4 a = *(const float4*)&sr[r][e0];
                float4 d = *(const float4*)&sr[r][e0 + 4];
                f16x8 h;
                h[0] = (_Float16)a.x; h[1] = (_Float16)a.y; h[2] = (_Float16)a.z; h[3] = (_Float16)a.w;
                h[4] = (_Float16)d.x; h[5] = (_Float16)d.y; h[6] = (_Float16)d.z; h[7] = (_Float16)d.w;
                *(f16x8*)&hout[((size_t)b * LL + row) * KG + e0] = h;
            }
        }
    }

    if (which == 1 && grp == 6 && b == 0) {
        for (int ent = t; ent < 640; ent += 256)
            *(f16x8*)&ksqt[(size_t)ent * 8] = *(const f16x8*)&kqf[ent * 8];
    }
}

// ---------------- maxsim: full-j, UNROLL-CONTROLLED pass loop, fused n1inv epilogue ------
// r11 post-mortem: full #pragma unroll on the 7-pass loop (28 ch-loop copies after pp nest)
// let the scheduler hoist loads across pass boundaries -> live-range blowup -> spill
// (FETCH 254 MB / WRITE 125 MB scratch). Fix: 6 UNIFORM 2-tile passes under #pragma
// unroll 1 (per-pass register demand = r10's proven steady state; loop boundary stops
// cross-pass hoisting) + peeled single-tile pass (rows 184-199, overlap; max idempotent).
// Structure otherwise = r11: B 200 rows + n2 + kq in LDS (147.8 KB, 1 block/CU), grid
// 256 = b x iblk x pgrp, one staging pass, out = rmax * n1inv written directly.
__global__ __launch_bounds__(256, 1) void maxsim_kernel(const _Float16* __restrict__ h1,
                                                        const _Float16* __restrict__ h2,
                                                        const _Float16* __restrict__ ksqt,
                                                        const _Float16* __restrict__ n2inv,
                                                        const float* __restrict__ n1inv,
                                                        float* __restrict__ out) {
    extern __shared__ __align__(16) char smem[];
    _Float16* h2s = (_Float16*)smem;          // 200*PS halfs = 131,200 B
    _Float16* n2s = h2s + 200 * PS;           // 200*16 halfs =   6,400 B
    _Float16* kqs = n2s + 200 * PP;           // 5120 halfs   =  10,240 B (total 147,840)

    const int blk  = blockIdx.x;
    const int b    = blk & 63;
    const int v    = blk >> 6;                // 0..3
    const int iblk = v & 1;
    const int pgrp = v >> 1;
    const int i0   = iblk ? 72 : 0;
    const int t    = threadIdx.x;

    const int lane = t & 63;
    const int w    = t >> 6;                  // 4 waves
    const int c    = lane & 15;
    const int quad = lane >> 4;
    const int ibase = i0 + w * 32;

    // A fragments: global -> registers (20 x b128 = 80 VGPR; h1 is L2/L3-hot)
    f16x8 af[2][NCH];
    {
        const _Float16* g1 = h1 + (size_t)b * LL * KG;
#pragma unroll
        for (int it = 0; it < 2; it++)
#pragma unroll
            for (int ch = 0; ch < NCH; ch++)
                af[it][ch] = *(const f16x8*)&g1[(size_t)(ibase + it * 16 + c) * KG + ch * 32 + quad * 8];
    }

    // stage FULL B tile (200 rows) + n2 (200 rows) + ksq table into LDS
    {
        const _Float16* g2 = h2 + (size_t)b * LL * KG;
        for (int idx = t; idx < 200 * 40; idx += 256) {
            int r = idx / 40, q = idx - r * 40;
            *(f16x8*)&h2s[r * PS + q * 8] = *(const f16x8*)&g2[(size_t)idx * 8];
        }
        const _Float16* gn = n2inv + (size_t)b * LL * PP;
        for (int idx = t; idx < 400; idx += 256)
            *(f16x8*)&n2s[idx * 8] = *(const f16x8*)&gn[(size_t)idx * 8];
        for (int idx = t; idx < 640; idx += 256)
            *(f16x8*)&kqs[idx * 8] = *(const f16x8*)&ksqt[(size_t)idx * 8];
    }
    __syncthreads();

    for (int pp = 0; pp < 4; pp++) {
        const int p0 = pgrp * 8 + pp * 2;
        float rmax[2][2][4];                   // [pq][it][r], persists across passes
#pragma unroll
        for (int pq = 0; pq < 2; pq++)
#pragma unroll
            for (int it = 0; it < 2; it++)
#pragma unroll
                for (int r = 0; r < 4; r++) rmax[pq][it][r] = -INFINITY;

        // ---- 6 uniform 2-tile passes (NOT unrolled: caps live ranges at r10's level) ----
#pragma unroll 1
        for (int pass = 0; pass < 6; pass++) {
            const int jb0 = pass * 32;
            const int jb1 = jb0 + 16;
            f32x4v acc[2][2][2];               // [pq][it][jt] = 64 acc regs
#pragma unroll
            for (int pq = 0; pq < 2; pq++)
#pragma unroll
                for (int it = 0; it < 2; it++)
#pragma unroll
                    for (int jt = 0; jt < 2; jt++) acc[pq][it][jt] = (f32x4v)0.f;

            f16x8 kq0 = *(const f16x8*)&kqs[quad * 128 + p0 * 8];
            f16x8 kq1 = *(const f16x8*)&kqs[quad * 128 + p0 * 8 + 8];
            f16x8 hb0 = *(const f16x8*)&h2s[(jb0 + c) * PS + quad * 8];
            f16x8 hb1 = *(const f16x8*)&h2s[(jb1 + c) * PS + quad * 8];

#pragma unroll
            for (int ch = 0; ch < NCH; ch++) {
                f16x8 kq0n = kq0, kq1n = kq1, hb0n = hb0, hb1n = hb1;
                if (ch < NCH - 1) {
                    kq0n = *(const f16x8*)&kqs[(ch + 1) * 512 + quad * 128 + p0 * 8];
                    kq1n = *(const f16x8*)&kqs[(ch + 1) * 512 + quad * 128 + p0 * 8 + 8];
                    hb0n = *(const f16x8*)&h2s[(jb0 + c) * PS + (ch + 1) * 32 + quad * 8];
                    hb1n = *(const f16x8*)&h2s[(jb1 + c) * PS + (ch + 1) * 32 + quad * 8];
                }
                f16x8 sa00 = af[0][ch] * kq0;
                f16x8 sa10 = af[1][ch] * kq0;
                f16x8 sa01 = af[0][ch] * kq1;
                f16x8 sa11 = af[1][ch] * kq1;
                acc[0][0][0] = __builtin_amdgcn_mfma_f32_16x16x32_f16(sa00, hb0, acc[0][0][0], 0, 0, 0);
                acc[0][1][0] = __builtin_amdgcn_mfma_f32_16x16x32_f16(sa10, hb0, acc[0][1][0], 0, 0, 0);
                acc[1][0][0] = __builtin_amdgcn_mfma_f32_16x16x32_f16(sa01, hb0, acc[1][0][0], 0, 0, 0);
                acc[1][1][0] = __builtin_amdgcn_mfma_f32_16x16x32_f16(sa11, hb0, acc[1][1][0], 0, 0, 0);
                acc[0][0][1] = __builtin_amdgcn_mfma_f32_16x16x32_f16(sa00, hb1, acc[0][0][1], 0, 0, 0);
                acc[0][1][1] = __builtin_amdgcn_mfma_f32_16x16x32_f16(sa10, hb1, acc[0][1][1], 0, 0, 0);
                acc[1][0][1] = __builtin_amdgcn_mfma_f32_16x16x32_f16(sa01, hb1, acc[1][0][1], 0, 0, 0);
                acc[1][1][1] = __builtin_amdgcn_mfma_f32_16x16x32_f16(sa11, hb1, acc[1][1][1], 0, 0, 0);
                kq0 = kq0n; kq1 = kq1n; hb0 = hb0n; hb1 = hb1n;
            }
#pragma unroll
            for (int pq = 0; pq < 2; pq++) {
                float n20 = (float)n2s[(jb0 + c) * PP + p0 + pq];
                float n21 = (float)n2s[(jb1 + c) * PP + p0 + pq];
#pragma unroll
                for (int it = 0; it < 2; it++)
#pragma unroll
                    for (int r = 0; r < 4; r++) {
                        rmax[pq][it][r] = fmaxf(rmax[pq][it][r], acc[pq][it][0][r] * n20);
                        rmax[pq][it][r] = fmaxf(rmax[pq][it][r], acc[pq][it][1][r] * n21);
                    }
            }
        }

        // ---- peeled final single-tile pass: rows 184..199 (overlap; max idempotent) ----
        {
            const int jb0 = 184;
            f32x4v acc[2][2];                  // [pq][it] = 32 acc regs
#pragma unroll
            for (int pq = 0; pq < 2; pq++)
#pragma unroll
                for (int it = 0; it < 2; it++) acc[pq][it] = (f32x4v)0.f;

            f16x8 kq0 = *(const f16x8*)&kqs[quad * 128 + p0 * 8];
            f16x8 kq1 = *(const f16x8*)&kqs[quad * 128 + p0 * 8 + 8];
            f16x8 hb0 = *(const f16x8*)&h2s[(jb0 + c) * PS + quad * 8];

#pragma unroll
            for (int ch = 0; ch < NCH; ch++) {
                f16x8 kq0n = kq0, kq1n = kq1, hb0n = hb0;
                if (ch < NCH - 1) {
                    kq0n = *(const f16x8*)&kqs[(ch + 1) * 512 + quad * 128 + p0 * 8];
                    kq1n = *(const f16x8*)&kqs[(ch + 1) * 512 + quad * 128 + p0 * 8 + 8];
                    hb0n = *(const f16x8*)&h2s[(jb0 + c) * PS + (ch + 1) * 32 + quad * 8];
                }
                f16x8 sa00 = af[0][ch] * kq0;
                f16x8 sa10 = af[1][ch] * kq0;
                f16x8 sa01 = af[0][ch] * kq1;
                f16x8 sa11 = af[1][ch] * kq1;
                acc[0][0] = __builtin_amdgcn_mfma_f32_16x16x32_f16(sa00, hb0, acc[0][0], 0, 0, 0);
                acc[0][1] = __builtin_amdgcn_mfma_f32_16x16x32_f16(sa10, hb0, acc[0][1], 0, 0, 0);
                acc[1][0] = __builtin_amdgcn_mfma_f32_16x16x32_f16(sa01, hb0, acc[1][0], 0, 0, 0);
                acc[1][1] = __builtin_amdgcn_mfma_f32_16x16x32_f16(sa11, hb0, acc[1][1], 0, 0, 0);
                kq0 = kq0n; kq1 = kq1n; hb0 = hb0n;
            }
#pragma unroll
            for (int pq = 0; pq < 2; pq++) {
                float n20 = (float)n2s[(jb0 + c) * PP + p0 + pq];
#pragma unroll
                for (int it = 0; it < 2; it++)
#pragma unroll
                    for (int r = 0; r < 4; r++)
                        rmax[pq][it][r] = fmaxf(rmax[pq][it][r], acc[pq][it][r] * n20);
            }
        }

        // reduce over j-col (lane bits 0..3), scale by n1inv, write out directly
#pragma unroll
        for (int pq = 0; pq < 2; pq++) {
#pragma unroll
            for (int m = 1; m <= 8; m <<= 1)
#pragma unroll
                for (int it = 0; it < 2; it++)
#pragma unroll
                    for (int r = 0; r < 4; r++)
                        rmax[pq][it][r] = fmaxf(rmax[pq][it][r], __shfl_xor(rmax[pq][it][r], m));
            if (c == 0) {
#pragma unroll
                for (int it = 0; it < 2; it++)
#pragma unroll
                    for (int r = 0; r < 4; r++) {
                        int i = ibase + it * 16 + quad * 4 + r;   // < 200 by construction
                        size_t o = ((size_t)b * LL + i) * PP + p0 + pq;
                        out[o] = rmax[pq][it][r] * n1inv[o];
                    }
            }
        }
    }
}

extern "C" void kernel_launch(void* const* d_in, const int* in_sizes, int n_in,
                              void* d_out, int out_size, void* d_ws, size_t ws_size,
                              hipStream_t stream) {
    const float* sent1  = (const float*)d_in[0];   // (64,200,300) f32
    const float* sent2  = (const float*)d_in[1];   // (64,200,300) f32
    const float* kernel = (const float*)d_in[2];   // (16,300)     f32
    float* out = (float*)d_out;                    // (64,200,16)  f32

    char* ws = (char*)d_ws;
    float*    n1inv = (float*)ws;                  ws += (size_t)BBATCH * LL * PP * 4;   // 0.82 MB
    _Float16* n2inv = (_Float16*)ws;               ws += (size_t)BBATCH * LL * PP * 2;   // 0.41 MB
    _Float16* h1    = (_Float16*)ws;               ws += (size_t)BBATCH * LL * KG * 2;   // 8.19 MB
    _Float16* h2    = (_Float16*)ws;               ws += (size_t)BBATCH * LL * KG * 2;   // 8.19 MB
    _Float16* ksqt  = (_Float16*)ws;               // 10 KB (total ~17.6 MB)

    prep_kernel<<<dim3(7, 2, BBATCH), 256, 0, stream>>>(sent1, sent2, kernel,
                                                        n1inv, n2inv, h1, h2, ksqt);

    const int lds_bytes = (200 * PS + 200 * PP + 5120) * 2;   // 147,840 B -> 1 block/CU
    hipFuncSetAttribute((const void*)maxsim_kernel,
                        hipFuncAttributeMaxDynamicSharedMemorySize, lds_bytes);
    maxsim_kernel<<<dim3(256, 1, 1), 256, lds_bytes, stream>>>(h1, h2, ksqt, n2inv, n1inv, out);
}